// Round 11
// baseline (349.665 us; speedup 1.0000x reference)
//
#include <hip/hip_runtime.h>
#include <math.h>

#define NB 8
#define NC 192
#define NH 56
#define NW 56
#define NN 3136      // NH*NW
#define NK 16        // clusters
#define KNB 9        // neighbors
#define NCOUT 384    // 2*NC
#define LPMAX 320    // max padded cluster size (L~196±14, 320 is >8 sigma)
#define DSTRIDE 320
#define DSLOT (320 * 320)

#define FLT_INF __builtin_inff()

typedef short s16x8 __attribute__((ext_vector_type(8)));
typedef _Float16 f16x8 __attribute__((ext_vector_type(8)));
typedef float f32x4 __attribute__((ext_vector_type(4)));
typedef unsigned short us8 __attribute__((ext_vector_type(8)));
typedef unsigned short us4 __attribute__((ext_vector_type(4)));

__device__ __forceinline__ float gelu_t(float x) {
    const float k0 = 0.7978845608028654f;
    float u = k0 * (x + 0.044715f * x * x * x);
    float t = tanhf(u);
    return 0.5f * x * (1.0f + t);
}

__device__ __forceinline__ unsigned short f2bf(float f) {
    unsigned u = __float_as_uint(f);
    u += 0x7fff + ((u >> 16) & 1);  // round-to-nearest-even
    return (unsigned short)(u >> 16);
}

__device__ __forceinline__ float bf2f(unsigned short h) {
    return __uint_as_float(((unsigned)h) << 16);
}

// ---------------- stable counting sort (self-contained: computes offsets too) ----------------
__global__ void order_kernel(const int* __restrict__ labels, int* __restrict__ order,
                             int* __restrict__ mapping, int* __restrict__ lsv,
                             int* __restrict__ cntk, int* __restrict__ offk) {
    int b = blockIdx.x >> 4;
    int k = blockIdx.x & 15;
    int lane = threadIdx.x;  // 64 threads
    const int* lb = labels + (size_t)b * NN;
    int cntLess = 0, cntEq = 0;
    for (int n0 = 0; n0 < NN; n0 += 64) {
        int lab = lb[n0 + lane] & 15;
        cntLess += __popcll(__ballot(lab < k));
        cntEq += __popcll(__ballot(lab == k));
    }
    int base = cntLess;
    int run = 0;
    for (int n0 = 0; n0 < NN; n0 += 64) {
        int n = n0 + lane;
        int lab = lb[n] & 15;
        bool p = (lab == k);
        unsigned long long mask = __ballot(p);
        int rank = __popcll(mask & ((1ull << lane) - 1ull));
        if (p) {
            int pos = base + run + rank;
            order[b * NN + pos] = n;
            mapping[b * NN + n] = pos;
            lsv[b * NN + pos] = k;
        }
        run += __popcll(mask);
    }
    if (lane == 0) {
        offk[b * NK + k] = base;
        cntk[b * NK + k] = cntEq;
    }
}

// ---------------- depthwise 7x7 conv + bias + residual -> bf16 xpe ----------------
__global__ __launch_bounds__(256) void conv_kernel(const float* __restrict__ X,
                                                   const float* __restrict__ W7,
                                                   const float* __restrict__ bias,
                                                   unsigned short* __restrict__ xpe) {
    __shared__ float tile[62 * 62];
    __shared__ float wl[49];
    int bc = blockIdx.x;  // b*NC + c
    int c = bc % NC;
    const float* Xp = X + (size_t)bc * NN;
    int tid = threadIdx.x;
    if (tid < 49) wl[tid] = W7[(size_t)c * 49 + tid];
    for (int idx = tid; idx < 62 * 62; idx += 256) {
        int ty = idx / 62, tx = idx % 62;
        int gy = ty - 3, gx = tx - 3;
        float v = 0.0f;
        if (gy >= 0 && gy < NH && gx >= 0 && gx < NW) v = Xp[gy * NW + gx];
        tile[idx] = v;
    }
    __syncthreads();
    float cb = bias[c];
    for (int g = tid; g < (NN / 4); g += 256) {
        int y = g / (NW / 4), x0 = (g % (NW / 4)) * 4;
        float a0 = 0.f, a1 = 0.f, a2 = 0.f, a3 = 0.f;
#pragma unroll
        for (int dy = 0; dy < 7; ++dy) {
            const float* tr = &tile[(y + dy) * 62 + x0];
#pragma unroll
            for (int dx = 0; dx < 7; ++dx) {
                float wv = wl[dy * 7 + dx];
                a0 += tr[dx] * wv;
                a1 += tr[dx + 1] * wv;
                a2 += tr[dx + 2] * wv;
                a3 += tr[dx + 3] * wv;
            }
        }
        const float* rr = &tile[(y + 3) * 62 + x0 + 3];
        us4 o;
        o[0] = f2bf(a0 + cb + rr[0]);
        o[1] = f2bf(a1 + cb + rr[1]);
        o[2] = f2bf(a2 + cb + rr[2]);
        o[3] = f2bf(a3 + cb + rr[3]);
        *(us4*)(xpe + (size_t)bc * NN + y * NW + x0) = o;
    }
}

// ---------------- ALL weight -> B-fragment conversions in one launch ----------------
__global__ void wcvt_all_kernel(const float* __restrict__ Wf1, const float* __restrict__ Wv,
                                const float* __restrict__ Wf2, unsigned short* __restrict__ wf1,
                                unsigned short* __restrict__ wfpmq,
                                unsigned short* __restrict__ wfq,
                                unsigned short* __restrict__ wf2) {
    int z = blockIdx.z, nt = blockIdx.x, kc = blockIdx.y;
    const float* W;
    unsigned short* Bf;
    int ldw, rowoff, KC, NT;
    bool diff = false;
    if (z == 0) { W = Wf1; Bf = wf1; ldw = NC; rowoff = 0; KC = 6; NT = 3; }
    else if (z == 1) { W = Wv; Bf = wfpmq; ldw = NCOUT; rowoff = 0; KC = 6; NT = 6; diff = true; }
    else if (z == 2) { W = Wv; Bf = wfq; ldw = NCOUT; rowoff = NC; KC = 6; NT = 6; }
    else { W = Wf2; Bf = wf2; ldw = NC; rowoff = 0; KC = 12; NT = 3; }
    if (nt >= NT || kc >= KC) return;
    int tid = threadIdx.x;  // 256
    int c = tid >> 6, l = tid & 63;
    int n = l & 15, q = l >> 4;
    int col = nt * 64 + c * 16 + n;
    int krow = rowoff + kc * 32 + q * 8;
    unsigned short pack[8];
#pragma unroll
    for (int j = 0; j < 8; ++j) {
        float v = W[(size_t)(krow + j) * ldw + col];
        if (diff) v -= W[(size_t)(NC + krow + j) * ldw + col];
        pack[j] = f2bf(v);
    }
    *(us8*)(Bf + ((((size_t)nt * KC + kc) * 4 + c) * 64 + l) * 8) = *(const us8*)pack;
}

// ---------------- bf16 xpe [b][c][n] -> A-fragment for fc1 (pure repack) ----------------
__global__ __launch_bounds__(256) void tcvt_kernel(const unsigned short* __restrict__ xpe,
                                                   unsigned short* __restrict__ Af) {
    __shared__ unsigned short t[32][72];
    int b = blockIdx.z, kc = blockIdx.y, n0 = blockIdx.x * 64;
    int tid = threadIdx.x;
    int cl = tid >> 3, nl = (tid & 7) * 8;
    const unsigned short* src = xpe + ((size_t)b * NC + kc * 32 + cl) * NN + n0 + nl;
    *(us8*)&t[cl][nl] = *(const us8*)src;
    __syncthreads();
    int w = tid >> 6, l = tid & 63;
    int m = l & 15, q = l >> 4;
    int nloc = w * 16 + m;
    unsigned short pack[8];
#pragma unroll
    for (int j = 0; j < 8; ++j) pack[j] = t[q * 8 + j][nloc];
    int sg = blockIdx.x * 4 + w;
    *(us8*)(Af + (size_t)b * NN * NC + (((size_t)sg * 6 + kc) * 64 + l) * 8) =
        *(const us8*)pack;
}

// ---------------- LDS-free MFMA GEMM: fragment-streaming, fp32 out (+opt scatter/frag) ----------------
template <int KC>
__global__ __launch_bounds__(256) void gemm_mfma(const unsigned short* __restrict__ Af,
                                                 size_t aStride,
                                                 const unsigned short* __restrict__ Bf,
                                                 const float* __restrict__ bias,
                                                 float* __restrict__ C, size_t cStride,
                                                 int ldc, unsigned short* __restrict__ Cfrag,
                                                 const int* __restrict__ rowmap) {
    int b = blockIdx.z;
    int w = threadIdx.x >> 6, lane = threadIdx.x & 63;
    int sg = blockIdx.y * 4 + w;
    int n0 = blockIdx.x * 64;
    const unsigned short* Ap = Af + (size_t)b * aStride + ((size_t)sg * KC * 64 + lane) * 8;
    const unsigned short* Bp = Bf + ((size_t)blockIdx.x * KC * 256 + lane) * 8;
    f32x4 acc[4] = {};
#pragma unroll
    for (int kc = 0; kc < KC; ++kc) {
        s16x8 a = *(const s16x8*)(Ap + kc * 512);
#pragma unroll
        for (int c = 0; c < 4; ++c) {
            s16x8 bv = *(const s16x8*)(Bp + kc * 2048 + c * 512);
            acc[c] = __builtin_amdgcn_mfma_f32_16x16x32_bf16(a, bv, acc[c], 0, 0, 0);
        }
    }
    int col0 = lane & 15, rq = lane >> 4;
    float* Cb = C + (size_t)b * cStride;
    int kcd = ldc >> 5;
#pragma unroll
    for (int r = 0; r < 4; ++r) {
        int grow = sg * 16 + rq * 4 + r;
        int orow = rowmap ? rowmap[(size_t)b * NN + grow] : grow;
#pragma unroll
        for (int c = 0; c < 4; ++c) {
            int col = n0 + c * 16 + col0;
            float v = acc[c][r];
            if (bias) v += bias[col];
            Cb[(size_t)orow * ldc + col] = v;
            if (Cfrag) {
                int s2 = orow >> 4, m2 = orow & 15;
                int kc2 = col >> 5, q2 = (col >> 3) & 3, j2 = col & 7;
                Cfrag[(size_t)b * cStride +
                      (((size_t)s2 * kcd + kc2) * 64 + q2 * 16 + m2) * 8 + j2] = f2bf(v);
            }
        }
    }
}

// ---------------- MFMA GEMM variant: bf16 row-major output only (Q) ----------------
template <int KC>
__global__ __launch_bounds__(256) void gemm_mfma_h(const unsigned short* __restrict__ Af,
                                                   size_t aStride,
                                                   const unsigned short* __restrict__ Bf,
                                                   unsigned short* __restrict__ C,
                                                   size_t cStride, int ldc) {
    int b = blockIdx.z;
    int w = threadIdx.x >> 6, lane = threadIdx.x & 63;
    int sg = blockIdx.y * 4 + w;
    int n0 = blockIdx.x * 64;
    const unsigned short* Ap = Af + (size_t)b * aStride + ((size_t)sg * KC * 64 + lane) * 8;
    const unsigned short* Bp = Bf + ((size_t)blockIdx.x * KC * 256 + lane) * 8;
    f32x4 acc[4] = {};
#pragma unroll
    for (int kc = 0; kc < KC; ++kc) {
        s16x8 a = *(const s16x8*)(Ap + kc * 512);
#pragma unroll
        for (int c = 0; c < 4; ++c) {
            s16x8 bv = *(const s16x8*)(Bp + kc * 2048 + c * 512);
            acc[c] = __builtin_amdgcn_mfma_f32_16x16x32_bf16(a, bv, acc[c], 0, 0, 0);
        }
    }
    int col0 = lane & 15, rq = lane >> 4;
    unsigned short* Cb = C + (size_t)b * cStride;
#pragma unroll
    for (int r = 0; r < 4; ++r) {
        int grow = sg * 16 + rq * 4 + r;
#pragma unroll
        for (int c = 0; c < 4; ++c) {
            int col = n0 + c * 16 + col0;
            Cb[(size_t)grow * ldc + col] = f2bf(acc[c][r]);
        }
    }
}

// ---------------- fc2: bf16 out + bias + row scatter ----------------
template <int KC>
__global__ __launch_bounds__(256) void gemm_mfma_hb(const unsigned short* __restrict__ Af,
                                                    size_t aStride,
                                                    const unsigned short* __restrict__ Bf,
                                                    const float* __restrict__ bias,
                                                    unsigned short* __restrict__ C,
                                                    size_t cStride, int ldc,
                                                    const int* __restrict__ rowmap) {
    int b = blockIdx.z;
    int w = threadIdx.x >> 6, lane = threadIdx.x & 63;
    int sg = blockIdx.y * 4 + w;
    int n0 = blockIdx.x * 64;
    const unsigned short* Ap = Af + (size_t)b * aStride + ((size_t)sg * KC * 64 + lane) * 8;
    const unsigned short* Bp = Bf + ((size_t)blockIdx.x * KC * 256 + lane) * 8;
    f32x4 acc[4] = {};
#pragma unroll
    for (int kc = 0; kc < KC; ++kc) {
        s16x8 a = *(const s16x8*)(Ap + kc * 512);
#pragma unroll
        for (int c = 0; c < 4; ++c) {
            s16x8 bv = *(const s16x8*)(Bp + kc * 2048 + c * 512);
            acc[c] = __builtin_amdgcn_mfma_f32_16x16x32_bf16(a, bv, acc[c], 0, 0, 0);
        }
    }
    int col0 = lane & 15, rq = lane >> 4;
    unsigned short* Cb = C + (size_t)b * cStride;
#pragma unroll
    for (int r = 0; r < 4; ++r) {
        int grow = sg * 16 + rq * 4 + r;
        int orow = rowmap[(size_t)b * NN + grow];
#pragma unroll
        for (int c = 0; c < 4; ++c) {
            int col = n0 + c * 16 + col0;
            Cb[(size_t)orow * ldc + col] = f2bf(acc[c][r] + bias[col]);
        }
    }
}

// ---------------- xe = xs*rinv -> fp16 A-fragments; computes rinv + sqv in-kernel ----------------
__global__ __launch_bounds__(384) void xe_cvt_kernel(const float* __restrict__ xs,
                                                     const int* __restrict__ offk,
                                                     const int* __restrict__ cntk,
                                                     _Float16* __restrict__ xef,
                                                     float* __restrict__ sqv) {
    __shared__ float psum[16][25];
    __shared__ float rloc[16];
    int b = blockIdx.z, k = blockIdx.y, strip = blockIdx.x;
    int bk = b * NK + k;
    int base = offk[bk], L = cntk[bk];
    if (strip * 16 >= L) return;
    int kc = threadIdx.x >> 6, l = threadIdx.x & 63;
    int m = l & 15, q = l >> 4;
    int rl = strip * 16 + m;
    int row = base + (rl < L ? rl : L - 1);
    const float* src = xs + ((size_t)b * NN + row) * NC + kc * 32 + q * 8;
    float4 v0 = *(const float4*)src;
    float4 v1 = *(const float4*)(src + 4);
    float part = v0.x * v0.x + v0.y * v0.y + v0.z * v0.z + v0.w * v0.w + v1.x * v1.x +
                 v1.y * v1.y + v1.z * v1.z + v1.w * v1.w;
    psum[m][kc * 4 + q] = part;
    __syncthreads();
    if (threadIdx.x < 16) {
        float s = 0.0f;
#pragma unroll
        for (int i2 = 0; i2 < 24; ++i2) s += psum[threadIdx.x][i2];
        float nrm = fmaxf(sqrtf(s), 1e-12f);
        float ri = 1.0f / nrm;
        rloc[threadIdx.x] = ri;
        if (strip * 16 + (int)threadIdx.x < L)
            sqv[(size_t)b * NN + base + strip * 16 + threadIdx.x] = (s * ri) * ri;
    }
    __syncthreads();
    float rv = rloc[m];
    f16x8 pack;
    pack[0] = (_Float16)(v0.x * rv);
    pack[1] = (_Float16)(v0.y * rv);
    pack[2] = (_Float16)(v0.z * rv);
    pack[3] = (_Float16)(v0.w * rv);
    pack[4] = (_Float16)(v1.x * rv);
    pack[5] = (_Float16)(v1.y * rv);
    pack[6] = (_Float16)(v1.z * rv);
    pack[7] = (_Float16)(v1.w * rv);
    *(f16x8*)(xef + (size_t)bk * (20 * 6 * 512) + (((size_t)strip * 6 + kc) * 64 + l) * 8) =
        pack;
}

// ---------------- Gram -> d2 tiles via fp16 MFMA (stores only live rows/cols) ----------------
__global__ __launch_bounds__(256) void gram_kernel(const _Float16* __restrict__ xef,
                                                   const float* __restrict__ sqv,
                                                   const int* __restrict__ offk,
                                                   const int* __restrict__ cntk,
                                                   float* __restrict__ D) {
    int bk = blockIdx.z;
    int b = bk >> 4;
    int base = offk[bk], L = cntk[bk];
    int ti = blockIdx.x, tj = blockIdx.y;
    if (ti * 64 >= L || tj * 64 >= L) return;
    int w = threadIdx.x >> 6, lane = threadIdx.x & 63;
    const _Float16* Xf = xef + (size_t)bk * (20 * 6 * 512);
    const _Float16* Ap = Xf + (((size_t)(ti * 4 + w) * 6) * 64 + lane) * 8;
    f32x4 acc[4] = {};
#pragma unroll
    for (int kc = 0; kc < 6; ++kc) {
        f16x8 a = *(const f16x8*)(Ap + kc * 512);
#pragma unroll
        for (int js = 0; js < 4; ++js) {
            f16x8 bv = *(const f16x8*)(Xf + (((size_t)(tj * 4 + js) * 6 + kc) * 64 + lane) * 8);
            acc[js] = __builtin_amdgcn_mfma_f32_16x16x32_f16(a, bv, acc[js], 0, 0, 0);
        }
    }
    float* Dr = D + (size_t)bk * DSLOT;
    const float* Sb = sqv + (size_t)b * NN + base;
    int col0 = lane & 15, rq = lane >> 4;
#pragma unroll
    for (int r = 0; r < 4; ++r) {
        int i = ti * 64 + w * 16 + rq * 4 + r;
        if (i >= L) continue;
        float si = Sb[i];
#pragma unroll
        for (int js = 0; js < 4; ++js) {
            int j = tj * 64 + js * 16 + col0;
            if (j < L) Dr[(size_t)i * DSTRIDE + j] = si + Sb[j] - 2.0f * acc[js][r];
        }
    }
}

// ---------------- top-9 selection: one wave per row (sorted ids) ----------------
#define LEXLT(da, ca, db, cb) ((da) < (db) || ((da) == (db) && (ca) < (cb)))
__global__ __launch_bounds__(256) void select9_kernel(const float* __restrict__ D,
                                                      const int* __restrict__ lsv,
                                                      const int* __restrict__ offk,
                                                      const int* __restrict__ cntk,
                                                      int* __restrict__ nbr) {
    int b = blockIdx.y;
    int r = blockIdx.x * 4 + (threadIdx.x >> 6);
    int lane = threadIdx.x & 63;
    int k = lsv[(size_t)b * NN + r];
    int bk = b * NK + k;
    int base = offk[bk], L = cntk[bk];
    int Lc = L < LPMAX ? L : LPMAX;
    const float* Dr = D + (size_t)bk * DSLOT + (size_t)(r - base) * DSTRIDE;
    float d0, d1, d2, d3, d4;
    int c0, c1, c2, c3, c4;
    c0 = lane;
    c1 = lane + 64;
    c2 = lane + 128;
    c3 = lane + 192;
    c4 = lane + 256;
    d0 = c0 < Lc ? Dr[c0] : FLT_INF;
    d1 = c1 < Lc ? Dr[c1] : FLT_INF;
    d2 = c2 < Lc ? Dr[c2] : FLT_INF;
    d3 = c3 < Lc ? Dr[c3] : FLT_INF;
    d4 = c4 < Lc ? Dr[c4] : FLT_INF;
#define CS(da, ca, db, cb)                  \
    if (LEXLT(db, cb, da, ca)) {            \
        float t = da; da = db; db = t;      \
        int u = ca; ca = cb; cb = u;        \
    }
    CS(d0, c0, d1, c1) CS(d3, c3, d4, c4) CS(d2, c2, d4, c4) CS(d2, c2, d3, c3)
    CS(d1, c1, d4, c4) CS(d0, c0, d3, c3) CS(d0, c0, d2, c2) CS(d1, c1, d3, c3)
    CS(d1, c1, d2, c2)
#undef CS
    size_t row = (size_t)b * NN + r;
    for (int q = 0; q < KNB; ++q) {
        float bd = d0;
        int bc = c0;
#pragma unroll
        for (int m = 32; m; m >>= 1) {
            float od = __shfl_xor(bd, m, 64);
            int oc = __shfl_xor(bc, m, 64);
            if (LEXLT(od, oc, bd, bc)) {
                bd = od;
                bc = oc;
            }
        }
        if (lane == 0) nbr[row * KNB + q] = base + bc;
        if (d0 == bd && c0 == bc) {
            d0 = d1; c0 = c1;
            d1 = d2; c1 = c2;
            d2 = d3; c2 = c3;
            d3 = d4; c3 = c4;
            d4 = FLT_INF; c4 = 0x7fffffff;
        }
    }
}

// ---------------- centroids: 768 threads, 4 row-partitions x 192 channels ----------------
__global__ __launch_bounds__(768) void cen_kernel(const float* __restrict__ xs,
                                                  const int* __restrict__ offk,
                                                  const int* __restrict__ cntk,
                                                  float* __restrict__ cen) {
    __shared__ float part[4][NC];
    int bk = blockIdx.x;
    int b = bk >> 4;
    int base = offk[bk], L = cntk[bk];
    int w = threadIdx.x / NC;  // 0..3 row partition
    int c = threadIdx.x % NC;
    const float* Xb = xs + ((size_t)b * NN + base) * NC + c;
    float s = 0.0f;
    for (int r = w; r < L; r += 4) s += Xb[(size_t)r * NC];
    part[w][c] = s;
    __syncthreads();
    if (threadIdx.x < NC) {
        int cc = threadIdx.x;
        float tot = part[0][cc] + part[1][cc] + part[2][cc] + part[3][cc];
        cen[(size_t)bk * NC + cc] = tot / fmaxf((float)L, 1.0f);
    }
}

// ---------------- merged cluster P/Q + valley max: one block per batch ----------------
__global__ __launch_bounds__(384) void pchc_kernel(const float* __restrict__ cen,
                                                   const float* __restrict__ Wc,
                                                   const float* __restrict__ bc,
                                                   float* __restrict__ hc) {
    __shared__ float ce[NK * NC];  // 12.3 KB
    int b = blockIdx.x;
    int o = threadIdx.x;  // 384
    for (int idx = o; idx < NK * NC; idx += 384) ce[idx] = cen[(size_t)b * NK * NC + idx];
    __syncthreads();
    float bcv = bc[o];
    float pc[NK], qc[NK];
#pragma unroll
    for (int k = 0; k < NK; ++k) {
        pc[k] = bcv;
        qc[k] = 0.0f;
    }
    for (int c = 0; c < NC; ++c) {
        float w1 = Wc[(size_t)c * NCOUT + o];
        float w2 = Wc[(size_t)(NC + c) * NCOUT + o];
#pragma unroll
        for (int k = 0; k < NK; ++k) {
            float cv = ce[k * NC + c];
            pc[k] += cv * w1;
            qc[k] += cv * w2;
        }
    }
    float qmn = qc[0], qmx = qc[0];
#pragma unroll
    for (int k = 1; k < NK; ++k) {
        qmn = fminf(qmn, qc[k]);
        qmx = fmaxf(qmx, qc[k]);
    }
#pragma unroll
    for (int i = 0; i < NK; ++i) {
        float pmq = pc[i] - qc[i];
        hc[((size_t)b * NK + i) * NCOUT + o] =
            fmaxf(gelu_t(pmq + qmn), gelu_t(pmq + qmx));
    }
}

// ---------------- node max + cluster term -> hn bf16 A-fragments (sorted order) ----------------
__global__ __launch_bounds__(256) void hv_kernel(const float* __restrict__ PmQ,
                                                 const unsigned short* __restrict__ Qh,
                                                 const int* __restrict__ nbr,
                                                 const int* __restrict__ lsv,
                                                 const float* __restrict__ hc,
                                                 unsigned short* __restrict__ hnf) {
    __shared__ float hnv[4][NCOUT];
    int b = blockIdx.y;
    int w = threadIdx.x >> 6, lane = threadIdx.x & 63;
    int i = blockIdx.x * 4 + w;
    size_t row = (size_t)b * NN + i;
    const float* Pr = PmQ + row * NCOUT;
    int lab = lsv[row];
    const float* hcr = hc + ((size_t)b * NK + lab) * NCOUT;
    int jn[KNB];
#pragma unroll
    for (int q = 0; q < KNB; ++q) jn[q] = nbr[row * KNB + q];
    const unsigned short* Qbb = Qh + (size_t)b * NN * NCOUT;
#pragma unroll
    for (int u = 0; u < 6; ++u) {
        int o = lane + 64 * u;
        float pmq = Pr[o];
        float q0 = bf2f(Qbb[(size_t)jn[0] * NCOUT + o]);
        float qmn = q0, qmx = q0;
#pragma unroll
        for (int q = 1; q < KNB; ++q) {
            float v = bf2f(Qbb[(size_t)jn[q] * NCOUT + o]);
            qmn = fminf(qmn, v);
            qmx = fmaxf(qmx, v);
        }
        float m = fmaxf(gelu_t(pmq + qmn), gelu_t(pmq + qmx));
        hnv[w][o] = m + hcr[o];
    }
    __syncthreads();
    if (threadIdx.x < 192) {  // 4 rows x 48 chunks of 8 -> us8 stores
        int rsub = threadIdx.x / 48, c = threadIdx.x % 48;
        int i2 = blockIdx.x * 4 + rsub;
        int s = i2 >> 4, mm = i2 & 15;
        unsigned short pack[8];
#pragma unroll
        for (int e = 0; e < 8; ++e) pack[e] = f2bf(hnv[rsub][c * 8 + e]);
        *(us8*)(hnf + (size_t)b * NN * NCOUT +
                (((size_t)s * 12 + (c >> 2)) * 64 + (c & 3) * 16 + mm) * 8) =
            *(const us8*)pack;
    }
}

// ---------------- transpose (b,n,c)->(b,c,n) + residual (bf16 in, fp32 out) ----------------
__global__ void out_kernel(const unsigned short* __restrict__ T, const float* __restrict__ X,
                           float* __restrict__ Y) {
    __shared__ float t[32][33];
    int b = blockIdx.z;
    int n0 = blockIdx.y * 32, c0 = blockIdx.x * 32;
    int tx = threadIdx.x, ty = threadIdx.y;  // 32 x 8
#pragma unroll
    for (int q = 0; q < 4; ++q) {
        int n = n0 + ty + q * 8;
        t[ty + q * 8][tx] = bf2f(T[((size_t)b * NN + n) * NC + c0 + tx]);
    }
    __syncthreads();
#pragma unroll
    for (int q = 0; q < 4; ++q) {
        int c = c0 + ty + q * 8;
        size_t idx = ((size_t)b * NC + c) * NN + n0 + tx;
        Y[idx] = t[tx][ty + q * 8] + X[idx];
    }
}

extern "C" void kernel_launch(void* const* d_in, const int* in_sizes, int n_in, void* d_out,
                              int out_size, void* d_ws, size_t ws_size, hipStream_t stream) {
    const float* x = (const float*)d_in[0];
    const int* labels = (const int*)d_in[1];
    const float* cpe_w = (const float*)d_in[2];
    const float* cpe_b = (const float*)d_in[3];
    const float* fc1_w = (const float*)d_in[4];
    const float* fc1_b = (const float*)d_in[5];
    const float* nn_v_w = (const float*)d_in[6];
    const float* nn_v_b = (const float*)d_in[7];
    const float* nn_c_w = (const float*)d_in[8];
    const float* nn_c_b = (const float*)d_in[9];
    const float* fc2_w = (const float*)d_in[10];
    const float* fc2_b = (const float*)d_in[11];
    float* out = (float*)d_out;

    const size_t SZ_XS = (size_t)NB * NN * NC;
    const size_t SZ_P = (size_t)NB * NN * NCOUT;
    const size_t BN = (size_t)NB * NN;
    const size_t SZ_CEN = (size_t)NB * NK * NC;
    const size_t SZ_PC = (size_t)NB * NK * NCOUT;

    float* base = (float*)d_ws;
    float* xs = base;                 // sorted fc1 out (fp32); reused as bf16 out_t after cen
    float* xpeRegion = xs + SZ_XS;    // bf16 conv out (ushort)
    float* Pb = xpeRegion + SZ_XS;    // PmQ (sorted); Dbuf during knn
    float* Qb = Pb + SZ_P;            // bf16 Qh (sorted, aliased)
    float* rinv = Qb + SZ_P;          // unused slot (kept for layout stability)
    float* sqv = rinv + BN;
    float* cen = sqv + BN;
    float* hcv = cen + SZ_CEN;
    int* order = (int*)(hcv + SZ_PC);
    int* mapping = order + BN;
    int* lsv = mapping + BN;
    int* nbrv = lsv + BN;
    int* cntk = nbrv + BN * KNB;
    int* offk = cntk + NB * NK;
    unsigned short* xpe = (unsigned short*)xpeRegion;
    float* Dbuf = Pb;  // spans Pb..Qb, dead before P/Q gemms
    unsigned short* Qh = (unsigned short*)Qb;
    unsigned short* out_t = (unsigned short*)xs;  // xs fp32 dead after cen
    unsigned short* frag = (unsigned short*)(offk + NB * NK);
    unsigned short* xpeT_frag = frag;
    unsigned short* xs_frag = frag + SZ_XS;
    unsigned short* hn_frag = frag;  // alias, xpeT dead by hv time
    unsigned short* wf1 = frag + 2 * SZ_XS;
    unsigned short* wfpmq = wf1 + (size_t)NC * NC;    // (Wtop-Wbot) 192x384
    unsigned short* wfq = wfpmq + (size_t)NC * NCOUT; // Wbot 192x384
    unsigned short* wf2 = wfq + (size_t)NC * NCOUT;
    _Float16* xef = (_Float16*)(wf2 + (size_t)NCOUT * NC);

    order_kernel<<<NB * NK, 64, 0, stream>>>(labels, order, mapping, lsv, cntk, offk);
    wcvt_all_kernel<<<dim3(6, 12, 4), 256, 0, stream>>>(fc1_w, nn_v_w, fc2_w, wf1, wfpmq,
                                                        wfq, wf2);
    conv_kernel<<<NB * NC, 256, 0, stream>>>(x, cpe_w, cpe_b, xpe);
    tcvt_kernel<<<dim3(NN / 64, NC / 32, NB), 256, 0, stream>>>(xpe, xpeT_frag);
    // fc1: rows scattered to sorted order; xs fp32 + xs_frag bf16 (sorted)
    gemm_mfma<6><<<dim3(NC / 64, NN / 64, NB), 256, 0, stream>>>(
        xpeT_frag, SZ_XS / NB, wf1, fc1_b, xs, (size_t)NN * NC, NC, xs_frag, mapping);
    // xe fragments + rinv/sqv fused
    xe_cvt_kernel<<<dim3(LPMAX / 16, NK, NB), 384, 0, stream>>>(xs, offk, cntk, xef, sqv);
    gram_kernel<<<dim3(LPMAX / 64, LPMAX / 64, NB * NK), 256, 0, stream>>>(xef, sqv, offk,
                                                                           cntk, Dbuf);
    select9_kernel<<<dim3(NN / 4, NB), 256, 0, stream>>>(Dbuf, lsv, offk, cntk, nbrv);
    // PmQ = xs @ (Wtop - Wbot) + bias_v  (fp32, sorted)
    gemm_mfma<6><<<dim3(NCOUT / 64, NN / 64, NB), 256, 0, stream>>>(
        xs_frag, SZ_XS / NB, wfpmq, nn_v_b, Pb, (size_t)NN * NCOUT, NCOUT, nullptr, nullptr);
    // Qh = xs @ Wbot  (bf16, sorted — consumed only by hv's gather)
    gemm_mfma_h<6><<<dim3(NCOUT / 64, NN / 64, NB), 256, 0, stream>>>(
        xs_frag, SZ_XS / NB, wfq, Qh, (size_t)NN * NCOUT, NCOUT);
    cen_kernel<<<NB * NK, 768, 0, stream>>>(xs, offk, cntk, cen);
    pchc_kernel<<<NB, 384, 0, stream>>>(cen, nn_c_w, nn_c_b, hcv);
    hv_kernel<<<dim3(NN / 4, NB), 256, 0, stream>>>(Pb, Qh, nbrv, lsv, hcv, hn_frag);
    // fc2: sorted rows -> bf16 out_t scattered to spatial order (xs region, fp32 xs dead)
    gemm_mfma_hb<12><<<dim3(NC / 64, NN / 64, NB), 256, 0, stream>>>(
        hn_frag, SZ_P / NB, wf2, fc2_b, out_t, (size_t)NN * NC, NC, order);
    out_kernel<<<dim3(NC / 32, NN / 32, NB), dim3(32, 8), 0, stream>>>(out_t, x, out);
}

// Round 12
// 325.010 us; speedup vs baseline: 1.0759x; 1.0759x over previous
//
#include <hip/hip_runtime.h>
#include <math.h>

#define NB 8
#define NC 192
#define NH 56
#define NW 56
#define NN 3136      // NH*NW
#define NK 16        // clusters
#define KNB 9        // neighbors
#define NCOUT 384    // 2*NC
#define LPMAX 320    // max padded cluster size (L~196±14, 320 is >8 sigma)
#define DSTRIDE 320
#define DSLOT (320 * 320)

#define FLT_INF __builtin_inff()

typedef short s16x8 __attribute__((ext_vector_type(8)));
typedef _Float16 f16x8 __attribute__((ext_vector_type(8)));
typedef float f32x4 __attribute__((ext_vector_type(4)));
typedef unsigned short us8 __attribute__((ext_vector_type(8)));
typedef unsigned short us4 __attribute__((ext_vector_type(4)));

__device__ __forceinline__ float gelu_t(float x) {
    const float k0 = 0.7978845608028654f;
    float u = k0 * (x + 0.044715f * x * x * x);
    float t = tanhf(u);
    return 0.5f * x * (1.0f + t);
}

__device__ __forceinline__ unsigned short f2bf(float f) {
    unsigned u = __float_as_uint(f);
    u += 0x7fff + ((u >> 16) & 1);  // round-to-nearest-even
    return (unsigned short)(u >> 16);
}

__device__ __forceinline__ float bf2f(unsigned short h) {
    return __uint_as_float(((unsigned)h) << 16);
}

// ---------------- stable counting sort (self-contained: computes offsets too) ----------------
__global__ void order_kernel(const int* __restrict__ labels, int* __restrict__ order,
                             int* __restrict__ mapping, int* __restrict__ lsv,
                             int* __restrict__ cntk, int* __restrict__ offk) {
    int b = blockIdx.x >> 4;
    int k = blockIdx.x & 15;
    int lane = threadIdx.x;  // 64 threads
    const int* lb = labels + (size_t)b * NN;
    int cntLess = 0, cntEq = 0;
    for (int n0 = 0; n0 < NN; n0 += 64) {
        int lab = lb[n0 + lane] & 15;
        cntLess += __popcll(__ballot(lab < k));
        cntEq += __popcll(__ballot(lab == k));
    }
    int base = cntLess;
    int run = 0;
    for (int n0 = 0; n0 < NN; n0 += 64) {
        int n = n0 + lane;
        int lab = lb[n] & 15;
        bool p = (lab == k);
        unsigned long long mask = __ballot(p);
        int rank = __popcll(mask & ((1ull << lane) - 1ull));
        if (p) {
            int pos = base + run + rank;
            order[b * NN + pos] = n;
            mapping[b * NN + n] = pos;
            lsv[b * NN + pos] = k;
        }
        run += __popcll(mask);
    }
    if (lane == 0) {
        offk[b * NK + k] = base;
        cntk[b * NK + k] = cntEq;
    }
}

// ---------------- depthwise 7x7 conv + bias + residual -> bf16 xpe ----------------
__global__ __launch_bounds__(256) void conv_kernel(const float* __restrict__ X,
                                                   const float* __restrict__ W7,
                                                   const float* __restrict__ bias,
                                                   unsigned short* __restrict__ xpe) {
    __shared__ float tile[62 * 62];
    __shared__ float wl[49];
    int bc = blockIdx.x;  // b*NC + c
    int c = bc % NC;
    const float* Xp = X + (size_t)bc * NN;
    int tid = threadIdx.x;
    if (tid < 49) wl[tid] = W7[(size_t)c * 49 + tid];
    for (int idx = tid; idx < 62 * 62; idx += 256) {
        int ty = idx / 62, tx = idx % 62;
        int gy = ty - 3, gx = tx - 3;
        float v = 0.0f;
        if (gy >= 0 && gy < NH && gx >= 0 && gx < NW) v = Xp[gy * NW + gx];
        tile[idx] = v;
    }
    __syncthreads();
    float cb = bias[c];
    for (int g = tid; g < (NN / 4); g += 256) {
        int y = g / (NW / 4), x0 = (g % (NW / 4)) * 4;
        float a0 = 0.f, a1 = 0.f, a2 = 0.f, a3 = 0.f;
#pragma unroll
        for (int dy = 0; dy < 7; ++dy) {
            const float* tr = &tile[(y + dy) * 62 + x0];
#pragma unroll
            for (int dx = 0; dx < 7; ++dx) {
                float wv = wl[dy * 7 + dx];
                a0 += tr[dx] * wv;
                a1 += tr[dx + 1] * wv;
                a2 += tr[dx + 2] * wv;
                a3 += tr[dx + 3] * wv;
            }
        }
        const float* rr = &tile[(y + 3) * 62 + x0 + 3];
        us4 o;
        o[0] = f2bf(a0 + cb + rr[0]);
        o[1] = f2bf(a1 + cb + rr[1]);
        o[2] = f2bf(a2 + cb + rr[2]);
        o[3] = f2bf(a3 + cb + rr[3]);
        *(us4*)(xpe + (size_t)bc * NN + y * NW + x0) = o;
    }
}

// ---------------- ALL weight -> B-fragment conversions in one launch ----------------
__global__ void wcvt_all_kernel(const float* __restrict__ Wf1, const float* __restrict__ Wv,
                                const float* __restrict__ Wf2, unsigned short* __restrict__ wf1,
                                unsigned short* __restrict__ wfpmq,
                                unsigned short* __restrict__ wfq,
                                unsigned short* __restrict__ wf2) {
    int z = blockIdx.z, nt = blockIdx.x, kc = blockIdx.y;
    const float* W;
    unsigned short* Bf;
    int ldw, rowoff, KC, NT;
    bool diff = false;
    if (z == 0) { W = Wf1; Bf = wf1; ldw = NC; rowoff = 0; KC = 6; NT = 3; }
    else if (z == 1) { W = Wv; Bf = wfpmq; ldw = NCOUT; rowoff = 0; KC = 6; NT = 6; diff = true; }
    else if (z == 2) { W = Wv; Bf = wfq; ldw = NCOUT; rowoff = NC; KC = 6; NT = 6; }
    else { W = Wf2; Bf = wf2; ldw = NC; rowoff = 0; KC = 12; NT = 3; }
    if (nt >= NT || kc >= KC) return;
    int tid = threadIdx.x;  // 256
    int c = tid >> 6, l = tid & 63;
    int n = l & 15, q = l >> 4;
    int col = nt * 64 + c * 16 + n;
    int krow = rowoff + kc * 32 + q * 8;
    unsigned short pack[8];
#pragma unroll
    for (int j = 0; j < 8; ++j) {
        float v = W[(size_t)(krow + j) * ldw + col];
        if (diff) v -= W[(size_t)(NC + krow + j) * ldw + col];
        pack[j] = f2bf(v);
    }
    *(us8*)(Bf + ((((size_t)nt * KC + kc) * 4 + c) * 64 + l) * 8) = *(const us8*)pack;
}

// ---------------- bf16 xpe [b][c][n] -> A-fragment for fc1 (pure repack) ----------------
__global__ __launch_bounds__(256) void tcvt_kernel(const unsigned short* __restrict__ xpe,
                                                   unsigned short* __restrict__ Af) {
    __shared__ unsigned short t[32][72];
    int b = blockIdx.z, kc = blockIdx.y, n0 = blockIdx.x * 64;
    int tid = threadIdx.x;
    int cl = tid >> 3, nl = (tid & 7) * 8;
    const unsigned short* src = xpe + ((size_t)b * NC + kc * 32 + cl) * NN + n0 + nl;
    *(us8*)&t[cl][nl] = *(const us8*)src;
    __syncthreads();
    int w = tid >> 6, l = tid & 63;
    int m = l & 15, q = l >> 4;
    int nloc = w * 16 + m;
    unsigned short pack[8];
#pragma unroll
    for (int j = 0; j < 8; ++j) pack[j] = t[q * 8 + j][nloc];
    int sg = blockIdx.x * 4 + w;
    *(us8*)(Af + (size_t)b * NN * NC + (((size_t)sg * 6 + kc) * 64 + l) * 8) =
        *(const us8*)pack;
}

// ---------------- LDS-free MFMA GEMM: fragment-streaming, fp32 out (+opt scatter/frag) ----------------
template <int KC>
__global__ __launch_bounds__(256) void gemm_mfma(const unsigned short* __restrict__ Af,
                                                 size_t aStride,
                                                 const unsigned short* __restrict__ Bf,
                                                 const float* __restrict__ bias,
                                                 float* __restrict__ C, size_t cStride,
                                                 int ldc, unsigned short* __restrict__ Cfrag,
                                                 const int* __restrict__ rowmap) {
    int b = blockIdx.z;
    int w = threadIdx.x >> 6, lane = threadIdx.x & 63;
    int sg = blockIdx.y * 4 + w;
    int n0 = blockIdx.x * 64;
    const unsigned short* Ap = Af + (size_t)b * aStride + ((size_t)sg * KC * 64 + lane) * 8;
    const unsigned short* Bp = Bf + ((size_t)blockIdx.x * KC * 256 + lane) * 8;
    f32x4 acc[4] = {};
#pragma unroll
    for (int kc = 0; kc < KC; ++kc) {
        s16x8 a = *(const s16x8*)(Ap + kc * 512);
#pragma unroll
        for (int c = 0; c < 4; ++c) {
            s16x8 bv = *(const s16x8*)(Bp + kc * 2048 + c * 512);
            acc[c] = __builtin_amdgcn_mfma_f32_16x16x32_bf16(a, bv, acc[c], 0, 0, 0);
        }
    }
    int col0 = lane & 15, rq = lane >> 4;
    float* Cb = C + (size_t)b * cStride;
    int kcd = ldc >> 5;
#pragma unroll
    for (int r = 0; r < 4; ++r) {
        int grow = sg * 16 + rq * 4 + r;
        int orow = rowmap ? rowmap[(size_t)b * NN + grow] : grow;
#pragma unroll
        for (int c = 0; c < 4; ++c) {
            int col = n0 + c * 16 + col0;
            float v = acc[c][r];
            if (bias) v += bias[col];
            Cb[(size_t)orow * ldc + col] = v;
            if (Cfrag) {
                int s2 = orow >> 4, m2 = orow & 15;
                int kc2 = col >> 5, q2 = (col >> 3) & 3, j2 = col & 7;
                Cfrag[(size_t)b * cStride +
                      (((size_t)s2 * kcd + kc2) * 64 + q2 * 16 + m2) * 8 + j2] = f2bf(v);
            }
        }
    }
}

// ---------------- MFMA GEMM variant: bf16 row-major output only (Q) ----------------
template <int KC>
__global__ __launch_bounds__(256) void gemm_mfma_h(const unsigned short* __restrict__ Af,
                                                   size_t aStride,
                                                   const unsigned short* __restrict__ Bf,
                                                   unsigned short* __restrict__ C,
                                                   size_t cStride, int ldc) {
    int b = blockIdx.z;
    int w = threadIdx.x >> 6, lane = threadIdx.x & 63;
    int sg = blockIdx.y * 4 + w;
    int n0 = blockIdx.x * 64;
    const unsigned short* Ap = Af + (size_t)b * aStride + ((size_t)sg * KC * 64 + lane) * 8;
    const unsigned short* Bp = Bf + ((size_t)blockIdx.x * KC * 256 + lane) * 8;
    f32x4 acc[4] = {};
#pragma unroll
    for (int kc = 0; kc < KC; ++kc) {
        s16x8 a = *(const s16x8*)(Ap + kc * 512);
#pragma unroll
        for (int c = 0; c < 4; ++c) {
            s16x8 bv = *(const s16x8*)(Bp + kc * 2048 + c * 512);
            acc[c] = __builtin_amdgcn_mfma_f32_16x16x32_bf16(a, bv, acc[c], 0, 0, 0);
        }
    }
    int col0 = lane & 15, rq = lane >> 4;
    unsigned short* Cb = C + (size_t)b * cStride;
#pragma unroll
    for (int r = 0; r < 4; ++r) {
        int grow = sg * 16 + rq * 4 + r;
#pragma unroll
        for (int c = 0; c < 4; ++c) {
            int col = n0 + c * 16 + col0;
            Cb[(size_t)grow * ldc + col] = f2bf(acc[c][r]);
        }
    }
}

// ---------------- fc2: bf16 out + bias + row scatter ----------------
template <int KC>
__global__ __launch_bounds__(256) void gemm_mfma_hb(const unsigned short* __restrict__ Af,
                                                    size_t aStride,
                                                    const unsigned short* __restrict__ Bf,
                                                    const float* __restrict__ bias,
                                                    unsigned short* __restrict__ C,
                                                    size_t cStride, int ldc,
                                                    const int* __restrict__ rowmap) {
    int b = blockIdx.z;
    int w = threadIdx.x >> 6, lane = threadIdx.x & 63;
    int sg = blockIdx.y * 4 + w;
    int n0 = blockIdx.x * 64;
    const unsigned short* Ap = Af + (size_t)b * aStride + ((size_t)sg * KC * 64 + lane) * 8;
    const unsigned short* Bp = Bf + ((size_t)blockIdx.x * KC * 256 + lane) * 8;
    f32x4 acc[4] = {};
#pragma unroll
    for (int kc = 0; kc < KC; ++kc) {
        s16x8 a = *(const s16x8*)(Ap + kc * 512);
#pragma unroll
        for (int c = 0; c < 4; ++c) {
            s16x8 bv = *(const s16x8*)(Bp + kc * 2048 + c * 512);
            acc[c] = __builtin_amdgcn_mfma_f32_16x16x32_bf16(a, bv, acc[c], 0, 0, 0);
        }
    }
    int col0 = lane & 15, rq = lane >> 4;
    unsigned short* Cb = C + (size_t)b * cStride;
#pragma unroll
    for (int r = 0; r < 4; ++r) {
        int grow = sg * 16 + rq * 4 + r;
        int orow = rowmap[(size_t)b * NN + grow];
#pragma unroll
        for (int c = 0; c < 4; ++c) {
            int col = n0 + c * 16 + col0;
            Cb[(size_t)orow * ldc + col] = f2bf(acc[c][r] + bias[col]);
        }
    }
}

// ---------------- xe = xs*rinv -> fp16 A-fragments; computes rinv + sqv in-kernel ----------------
__global__ __launch_bounds__(384) void xe_cvt_kernel(const float* __restrict__ xs,
                                                     const int* __restrict__ offk,
                                                     const int* __restrict__ cntk,
                                                     _Float16* __restrict__ xef,
                                                     float* __restrict__ sqv) {
    __shared__ float psum[16][25];
    __shared__ float rloc[16];
    int b = blockIdx.z, k = blockIdx.y, strip = blockIdx.x;
    int bk = b * NK + k;
    int base = offk[bk], L = cntk[bk];
    if (strip * 16 >= L) return;
    int kc = threadIdx.x >> 6, l = threadIdx.x & 63;
    int m = l & 15, q = l >> 4;
    int rl = strip * 16 + m;
    int row = base + (rl < L ? rl : L - 1);
    const float* src = xs + ((size_t)b * NN + row) * NC + kc * 32 + q * 8;
    float4 v0 = *(const float4*)src;
    float4 v1 = *(const float4*)(src + 4);
    float part = v0.x * v0.x + v0.y * v0.y + v0.z * v0.z + v0.w * v0.w + v1.x * v1.x +
                 v1.y * v1.y + v1.z * v1.z + v1.w * v1.w;
    psum[m][kc * 4 + q] = part;
    __syncthreads();
    if (threadIdx.x < 16) {
        float s = 0.0f;
#pragma unroll
        for (int i2 = 0; i2 < 24; ++i2) s += psum[threadIdx.x][i2];
        float nrm = fmaxf(sqrtf(s), 1e-12f);
        float ri = 1.0f / nrm;
        rloc[threadIdx.x] = ri;
        if (strip * 16 + (int)threadIdx.x < L)
            sqv[(size_t)b * NN + base + strip * 16 + threadIdx.x] = (s * ri) * ri;
    }
    __syncthreads();
    float rv = rloc[m];
    f16x8 pack;
    pack[0] = (_Float16)(v0.x * rv);
    pack[1] = (_Float16)(v0.y * rv);
    pack[2] = (_Float16)(v0.z * rv);
    pack[3] = (_Float16)(v0.w * rv);
    pack[4] = (_Float16)(v1.x * rv);
    pack[5] = (_Float16)(v1.y * rv);
    pack[6] = (_Float16)(v1.z * rv);
    pack[7] = (_Float16)(v1.w * rv);
    *(f16x8*)(xef + (size_t)bk * (20 * 6 * 512) + (((size_t)strip * 6 + kc) * 64 + l) * 8) =
        pack;
}

// ---------------- Gram -> d2 tiles via fp16 MFMA (stores only live rows/cols) ----------------
__global__ __launch_bounds__(256) void gram_kernel(const _Float16* __restrict__ xef,
                                                   const float* __restrict__ sqv,
                                                   const int* __restrict__ offk,
                                                   const int* __restrict__ cntk,
                                                   float* __restrict__ D) {
    int bk = blockIdx.z;
    int b = bk >> 4;
    int base = offk[bk], L = cntk[bk];
    int ti = blockIdx.x, tj = blockIdx.y;
    if (ti * 64 >= L || tj * 64 >= L) return;
    int w = threadIdx.x >> 6, lane = threadIdx.x & 63;
    const _Float16* Xf = xef + (size_t)bk * (20 * 6 * 512);
    const _Float16* Ap = Xf + (((size_t)(ti * 4 + w) * 6) * 64 + lane) * 8;
    f32x4 acc[4] = {};
#pragma unroll
    for (int kc = 0; kc < 6; ++kc) {
        f16x8 a = *(const f16x8*)(Ap + kc * 512);
#pragma unroll
        for (int js = 0; js < 4; ++js) {
            f16x8 bv = *(const f16x8*)(Xf + (((size_t)(tj * 4 + js) * 6 + kc) * 64 + lane) * 8);
            acc[js] = __builtin_amdgcn_mfma_f32_16x16x32_f16(a, bv, acc[js], 0, 0, 0);
        }
    }
    float* Dr = D + (size_t)bk * DSLOT;
    const float* Sb = sqv + (size_t)b * NN + base;
    int col0 = lane & 15, rq = lane >> 4;
#pragma unroll
    for (int r = 0; r < 4; ++r) {
        int i = ti * 64 + w * 16 + rq * 4 + r;
        if (i >= L) continue;
        float si = Sb[i];
#pragma unroll
        for (int js = 0; js < 4; ++js) {
            int j = tj * 64 + js * 16 + col0;
            if (j < L) Dr[(size_t)i * DSTRIDE + j] = si + Sb[j] - 2.0f * acc[js][r];
        }
    }
}

// ---------------- top-9 selection: one wave per row (sorted ids) ----------------
#define LEXLT(da, ca, db, cb) ((da) < (db) || ((da) == (db) && (ca) < (cb)))
__global__ __launch_bounds__(256) void select9_kernel(const float* __restrict__ D,
                                                      const int* __restrict__ lsv,
                                                      const int* __restrict__ offk,
                                                      const int* __restrict__ cntk,
                                                      int* __restrict__ nbr) {
    int b = blockIdx.y;
    int r = blockIdx.x * 4 + (threadIdx.x >> 6);
    int lane = threadIdx.x & 63;
    int k = lsv[(size_t)b * NN + r];
    int bk = b * NK + k;
    int base = offk[bk], L = cntk[bk];
    int Lc = L < LPMAX ? L : LPMAX;
    const float* Dr = D + (size_t)bk * DSLOT + (size_t)(r - base) * DSTRIDE;
    float d0, d1, d2, d3, d4;
    int c0, c1, c2, c3, c4;
    c0 = lane;
    c1 = lane + 64;
    c2 = lane + 128;
    c3 = lane + 192;
    c4 = lane + 256;
    d0 = c0 < Lc ? Dr[c0] : FLT_INF;
    d1 = c1 < Lc ? Dr[c1] : FLT_INF;
    d2 = c2 < Lc ? Dr[c2] : FLT_INF;
    d3 = c3 < Lc ? Dr[c3] : FLT_INF;
    d4 = c4 < Lc ? Dr[c4] : FLT_INF;
#define CS(da, ca, db, cb)                  \
    if (LEXLT(db, cb, da, ca)) {            \
        float t = da; da = db; db = t;      \
        int u = ca; ca = cb; cb = u;        \
    }
    CS(d0, c0, d1, c1) CS(d3, c3, d4, c4) CS(d2, c2, d4, c4) CS(d2, c2, d3, c3)
    CS(d1, c1, d4, c4) CS(d0, c0, d3, c3) CS(d0, c0, d2, c2) CS(d1, c1, d3, c3)
    CS(d1, c1, d2, c2)
#undef CS
    size_t row = (size_t)b * NN + r;
    for (int q = 0; q < KNB; ++q) {
        float bd = d0;
        int bc = c0;
#pragma unroll
        for (int m = 32; m; m >>= 1) {
            float od = __shfl_xor(bd, m, 64);
            int oc = __shfl_xor(bc, m, 64);
            if (LEXLT(od, oc, bd, bc)) {
                bd = od;
                bc = oc;
            }
        }
        if (lane == 0) nbr[row * KNB + q] = base + bc;
        if (d0 == bd && c0 == bc) {
            d0 = d1; c0 = c1;
            d1 = d2; c1 = c2;
            d2 = d3; c2 = c3;
            d3 = d4; c3 = c4;
            d4 = FLT_INF; c4 = 0x7fffffff;
        }
    }
}

// ---------------- centroids: 768 threads, 4 row-partitions x 192 channels ----------------
__global__ __launch_bounds__(768) void cen_kernel(const float* __restrict__ xs,
                                                  const int* __restrict__ offk,
                                                  const int* __restrict__ cntk,
                                                  float* __restrict__ cen) {
    __shared__ float part[4][NC];
    int bk = blockIdx.x;
    int b = bk >> 4;
    int base = offk[bk], L = cntk[bk];
    int w = threadIdx.x / NC;  // 0..3 row partition
    int c = threadIdx.x % NC;
    const float* Xb = xs + ((size_t)b * NN + base) * NC + c;
    float s = 0.0f;
    for (int r = w; r < L; r += 4) s += Xb[(size_t)r * NC];
    part[w][c] = s;
    __syncthreads();
    if (threadIdx.x < NC) {
        int cc = threadIdx.x;
        float tot = part[0][cc] + part[1][cc] + part[2][cc] + part[3][cc];
        cen[(size_t)bk * NC + cc] = tot / fmaxf((float)L, 1.0f);
    }
}

// ---------------- cluster P/Q (128 blocks) ----------------
__global__ __launch_bounds__(384) void pcqc_kernel(const float* __restrict__ cen,
                                                   const float* __restrict__ Wc,
                                                   const float* __restrict__ bc,
                                                   float* __restrict__ Pc,
                                                   float* __restrict__ Qc) {
    __shared__ float ce[NC];
    int bk = blockIdx.x;
    int o = threadIdx.x;  // 384
    if (o < NC) ce[o] = cen[(size_t)bk * NC + o];
    __syncthreads();
    float pc = bc[o], qc = 0.0f;
    for (int c = 0; c < NC; ++c) {
        pc += ce[c] * Wc[(size_t)c * NCOUT + o];
        qc += ce[c] * Wc[(size_t)(NC + c) * NCOUT + o];
    }
    Pc[(size_t)bk * NCOUT + o] = pc;
    Qc[(size_t)bk * NCOUT + o] = qc;
}

// ---------------- cluster message max (valley trick, 128 blocks) ----------------
__global__ __launch_bounds__(384) void hcmax_kernel(const float* __restrict__ Pc,
                                                    const float* __restrict__ Qc,
                                                    float* __restrict__ hc) {
    int b = blockIdx.x >> 4, i = blockIdx.x & 15;
    int o = threadIdx.x;
    float pi = Pc[((size_t)b * NK + i) * NCOUT + o];
    float qi = Qc[((size_t)b * NK + i) * NCOUT + o];
    float pmq = pi - qi;
    float qmn = FLT_INF, qmx = -FLT_INF;
    for (int j = 0; j < NK; ++j) {
        float v = Qc[((size_t)b * NK + j) * NCOUT + o];
        qmn = fminf(qmn, v);
        qmx = fmaxf(qmx, v);
    }
    hc[((size_t)b * NK + i) * NCOUT + o] =
        fmaxf(gelu_t(pmq + qmn), gelu_t(pmq + qmx));
}

// ---------------- node max + cluster term -> hn bf16 A-fragments (sorted order) ----------------
__global__ __launch_bounds__(256) void hv_kernel(const float* __restrict__ PmQ,
                                                 const unsigned short* __restrict__ Qh,
                                                 const int* __restrict__ nbr,
                                                 const int* __restrict__ lsv,
                                                 const float* __restrict__ hc,
                                                 unsigned short* __restrict__ hnf) {
    __shared__ float hnv[4][NCOUT];
    int b = blockIdx.y;
    int w = threadIdx.x >> 6, lane = threadIdx.x & 63;
    int i = blockIdx.x * 4 + w;
    size_t row = (size_t)b * NN + i;
    const float* Pr = PmQ + row * NCOUT;
    int lab = lsv[row];
    const float* hcr = hc + ((size_t)b * NK + lab) * NCOUT;
    int jn[KNB];
#pragma unroll
    for (int q = 0; q < KNB; ++q) jn[q] = nbr[row * KNB + q];
    const unsigned short* Qbb = Qh + (size_t)b * NN * NCOUT;
#pragma unroll
    for (int u = 0; u < 6; ++u) {
        int o = lane + 64 * u;
        float pmq = Pr[o];
        float q0 = bf2f(Qbb[(size_t)jn[0] * NCOUT + o]);
        float qmn = q0, qmx = q0;
#pragma unroll
        for (int q = 1; q < KNB; ++q) {
            float v = bf2f(Qbb[(size_t)jn[q] * NCOUT + o]);
            qmn = fminf(qmn, v);
            qmx = fmaxf(qmx, v);
        }
        float m = fmaxf(gelu_t(pmq + qmn), gelu_t(pmq + qmx));
        hnv[w][o] = m + hcr[o];
    }
    __syncthreads();
    if (threadIdx.x < 192) {  // 4 rows x 48 chunks of 8 -> us8 stores
        int rsub = threadIdx.x / 48, c = threadIdx.x % 48;
        int i2 = blockIdx.x * 4 + rsub;
        int s = i2 >> 4, mm = i2 & 15;
        unsigned short pack[8];
#pragma unroll
        for (int e = 0; e < 8; ++e) pack[e] = f2bf(hnv[rsub][c * 8 + e]);
        *(us8*)(hnf + (size_t)b * NN * NCOUT +
                (((size_t)s * 12 + (c >> 2)) * 64 + (c & 3) * 16 + mm) * 8) =
            *(const us8*)pack;
    }
}

// ---------------- transpose (b,n,c)->(b,c,n) + residual (bf16 in, fp32 out) ----------------
__global__ void out_kernel(const unsigned short* __restrict__ T, const float* __restrict__ X,
                           float* __restrict__ Y) {
    __shared__ float t[32][33];
    int b = blockIdx.z;
    int n0 = blockIdx.y * 32, c0 = blockIdx.x * 32;
    int tx = threadIdx.x, ty = threadIdx.y;  // 32 x 8
#pragma unroll
    for (int q = 0; q < 4; ++q) {
        int n = n0 + ty + q * 8;
        t[ty + q * 8][tx] = bf2f(T[((size_t)b * NN + n) * NC + c0 + tx]);
    }
    __syncthreads();
#pragma unroll
    for (int q = 0; q < 4; ++q) {
        int c = c0 + ty + q * 8;
        size_t idx = ((size_t)b * NC + c) * NN + n0 + tx;
        Y[idx] = t[tx][ty + q * 8] + X[idx];
    }
}

extern "C" void kernel_launch(void* const* d_in, const int* in_sizes, int n_in, void* d_out,
                              int out_size, void* d_ws, size_t ws_size, hipStream_t stream) {
    const float* x = (const float*)d_in[0];
    const int* labels = (const int*)d_in[1];
    const float* cpe_w = (const float*)d_in[2];
    const float* cpe_b = (const float*)d_in[3];
    const float* fc1_w = (const float*)d_in[4];
    const float* fc1_b = (const float*)d_in[5];
    const float* nn_v_w = (const float*)d_in[6];
    const float* nn_v_b = (const float*)d_in[7];
    const float* nn_c_w = (const float*)d_in[8];
    const float* nn_c_b = (const float*)d_in[9];
    const float* fc2_w = (const float*)d_in[10];
    const float* fc2_b = (const float*)d_in[11];
    float* out = (float*)d_out;

    const size_t SZ_XS = (size_t)NB * NN * NC;
    const size_t SZ_P = (size_t)NB * NN * NCOUT;
    const size_t BN = (size_t)NB * NN;
    const size_t SZ_CEN = (size_t)NB * NK * NC;
    const size_t SZ_PC = (size_t)NB * NK * NCOUT;

    float* base = (float*)d_ws;
    float* xs = base;                 // sorted fc1 out (fp32); reused as bf16 out_t after cen
    float* xpeRegion = xs + SZ_XS;    // bf16 conv out (ushort)
    float* Pb = xpeRegion + SZ_XS;    // PmQ (sorted); Dbuf during knn
    float* Qb = Pb + SZ_P;            // bf16 Qh (sorted, aliased)
    float* rinv = Qb + SZ_P;          // unused slot (kept for layout stability)
    float* sqv = rinv + BN;
    float* cen = sqv + BN;
    float* Pc = cen + SZ_CEN;
    float* Qc = Pc + SZ_PC;
    float* hcv = Qc + SZ_PC;
    int* order = (int*)(hcv + SZ_PC);
    int* mapping = order + BN;
    int* lsv = mapping + BN;
    int* nbrv = lsv + BN;
    int* cntk = nbrv + BN * KNB;
    int* offk = cntk + NB * NK;
    unsigned short* xpe = (unsigned short*)xpeRegion;
    float* Dbuf = Pb;  // spans Pb..Qb, dead before P/Q gemms
    unsigned short* Qh = (unsigned short*)Qb;
    unsigned short* out_t = (unsigned short*)xs;  // xs fp32 dead after cen
    unsigned short* frag = (unsigned short*)(offk + NB * NK);
    unsigned short* xpeT_frag = frag;
    unsigned short* xs_frag = frag + SZ_XS;
    unsigned short* hn_frag = frag;  // alias, xpeT dead by hv time
    unsigned short* wf1 = frag + 2 * SZ_XS;
    unsigned short* wfpmq = wf1 + (size_t)NC * NC;    // (Wtop-Wbot) 192x384
    unsigned short* wfq = wfpmq + (size_t)NC * NCOUT; // Wbot 192x384
    unsigned short* wf2 = wfq + (size_t)NC * NCOUT;
    _Float16* xef = (_Float16*)(wf2 + (size_t)NCOUT * NC);

    order_kernel<<<NB * NK, 64, 0, stream>>>(labels, order, mapping, lsv, cntk, offk);
    wcvt_all_kernel<<<dim3(6, 12, 4), 256, 0, stream>>>(fc1_w, nn_v_w, fc2_w, wf1, wfpmq,
                                                        wfq, wf2);
    conv_kernel<<<NB * NC, 256, 0, stream>>>(x, cpe_w, cpe_b, xpe);
    tcvt_kernel<<<dim3(NN / 64, NC / 32, NB), 256, 0, stream>>>(xpe, xpeT_frag);
    // fc1: rows scattered to sorted order; xs fp32 + xs_frag bf16 (sorted)
    gemm_mfma<6><<<dim3(NC / 64, NN / 64, NB), 256, 0, stream>>>(
        xpeT_frag, SZ_XS / NB, wf1, fc1_b, xs, (size_t)NN * NC, NC, xs_frag, mapping);
    // xe fragments + rinv/sqv fused
    xe_cvt_kernel<<<dim3(LPMAX / 16, NK, NB), 384, 0, stream>>>(xs, offk, cntk, xef, sqv);
    gram_kernel<<<dim3(LPMAX / 64, LPMAX / 64, NB * NK), 256, 0, stream>>>(xef, sqv, offk,
                                                                           cntk, Dbuf);
    select9_kernel<<<dim3(NN / 4, NB), 256, 0, stream>>>(Dbuf, lsv, offk, cntk, nbrv);
    // PmQ = xs @ (Wtop - Wbot) + bias_v  (fp32, sorted)
    gemm_mfma<6><<<dim3(NCOUT / 64, NN / 64, NB), 256, 0, stream>>>(
        xs_frag, SZ_XS / NB, wfpmq, nn_v_b, Pb, (size_t)NN * NCOUT, NCOUT, nullptr, nullptr);
    // Qh = xs @ Wbot  (bf16, sorted — consumed only by hv's gather)
    gemm_mfma_h<6><<<dim3(NCOUT / 64, NN / 64, NB), 256, 0, stream>>>(
        xs_frag, SZ_XS / NB, wfq, Qh, (size_t)NN * NCOUT, NCOUT);
    cen_kernel<<<NB * NK, 768, 0, stream>>>(xs, offk, cntk, cen);
    pcqc_kernel<<<NB * NK, NCOUT, 0, stream>>>(cen, nn_c_w, nn_c_b, Pc, Qc);
    hcmax_kernel<<<NB * NK, NCOUT, 0, stream>>>(Pc, Qc, hcv);
    hv_kernel<<<dim3(NN / 4, NB), 256, 0, stream>>>(Pb, Qh, nbrv, lsv, hcv, hn_frag);
    // fc2: sorted rows -> bf16 out_t scattered to spatial order (xs region, fp32 xs dead)
    gemm_mfma_hb<12><<<dim3(NC / 64, NN / 64, NB), 256, 0, stream>>>(
        hn_frag, SZ_P / NB, wf2, fc2_b, out_t, (size_t)NN * NC, NC, order);
    out_kernel<<<dim3(NC / 32, NN / 32, NB), dim3(32, 8), 0, stream>>>(out_t, x, out);
}

// Round 13
// 322.540 us; speedup vs baseline: 1.0841x; 1.0077x over previous
//
#include <hip/hip_runtime.h>
#include <math.h>

#define NB 8
#define NC 192
#define NH 56
#define NW 56
#define NN 3136      // NH*NW
#define NK 16        // clusters
#define KNB 9        // neighbors
#define NCOUT 384    // 2*NC
#define LPMAX 320    // max padded cluster size (L~196±14, 320 is >8 sigma)
#define DSTRIDE 320
#define DSLOT (320 * 320)

#define FLT_INF __builtin_inff()

typedef short s16x8 __attribute__((ext_vector_type(8)));
typedef _Float16 f16x8 __attribute__((ext_vector_type(8)));
typedef float f32x4 __attribute__((ext_vector_type(4)));
typedef unsigned short us8 __attribute__((ext_vector_type(8)));
typedef unsigned short us4 __attribute__((ext_vector_type(4)));

__device__ __forceinline__ float gelu_t(float x) {
    const float k0 = 0.7978845608028654f;
    float u = k0 * (x + 0.044715f * x * x * x);
    float t = tanhf(u);
    return 0.5f * x * (1.0f + t);
}

__device__ __forceinline__ unsigned short f2bf(float f) {
    unsigned u = __float_as_uint(f);
    u += 0x7fff + ((u >> 16) & 1);  // round-to-nearest-even
    return (unsigned short)(u >> 16);
}

__device__ __forceinline__ float bf2f(unsigned short h) {
    return __uint_as_float(((unsigned)h) << 16);
}

// ---------------- stable counting sort (self-contained: computes offsets too) ----------------
__global__ void order_kernel(const int* __restrict__ labels, int* __restrict__ order,
                             int* __restrict__ mapping, int* __restrict__ lsv,
                             int* __restrict__ cntk, int* __restrict__ offk) {
    int b = blockIdx.x >> 4;
    int k = blockIdx.x & 15;
    int lane = threadIdx.x;  // 64 threads
    const int* lb = labels + (size_t)b * NN;
    int cntLess = 0, cntEq = 0;
    for (int n0 = 0; n0 < NN; n0 += 64) {
        int lab = lb[n0 + lane] & 15;
        cntLess += __popcll(__ballot(lab < k));
        cntEq += __popcll(__ballot(lab == k));
    }
    int base = cntLess;
    int run = 0;
    for (int n0 = 0; n0 < NN; n0 += 64) {
        int n = n0 + lane;
        int lab = lb[n] & 15;
        bool p = (lab == k);
        unsigned long long mask = __ballot(p);
        int rank = __popcll(mask & ((1ull << lane) - 1ull));
        if (p) {
            int pos = base + run + rank;
            order[b * NN + pos] = n;
            mapping[b * NN + n] = pos;
            lsv[b * NN + pos] = k;
        }
        run += __popcll(mask);
    }
    if (lane == 0) {
        offk[b * NK + k] = base;
        cntk[b * NK + k] = cntEq;
    }
}

// ---------------- depthwise 7x7 conv + bias + residual -> bf16 xpe ----------------
__global__ __launch_bounds__(256) void conv_kernel(const float* __restrict__ X,
                                                   const float* __restrict__ W7,
                                                   const float* __restrict__ bias,
                                                   unsigned short* __restrict__ xpe) {
    __shared__ float tile[62 * 62];
    __shared__ float wl[49];
    int bc = blockIdx.x;  // b*NC + c
    int c = bc % NC;
    const float* Xp = X + (size_t)bc * NN;
    int tid = threadIdx.x;
    if (tid < 49) wl[tid] = W7[(size_t)c * 49 + tid];
    for (int idx = tid; idx < 62 * 62; idx += 256) {
        int ty = idx / 62, tx = idx % 62;
        int gy = ty - 3, gx = tx - 3;
        float v = 0.0f;
        if (gy >= 0 && gy < NH && gx >= 0 && gx < NW) v = Xp[gy * NW + gx];
        tile[idx] = v;
    }
    __syncthreads();
    float cb = bias[c];
    for (int g = tid; g < (NN / 4); g += 256) {
        int y = g / (NW / 4), x0 = (g % (NW / 4)) * 4;
        float a0 = 0.f, a1 = 0.f, a2 = 0.f, a3 = 0.f;
#pragma unroll
        for (int dy = 0; dy < 7; ++dy) {
            const float* tr = &tile[(y + dy) * 62 + x0];
#pragma unroll
            for (int dx = 0; dx < 7; ++dx) {
                float wv = wl[dy * 7 + dx];
                a0 += tr[dx] * wv;
                a1 += tr[dx + 1] * wv;
                a2 += tr[dx + 2] * wv;
                a3 += tr[dx + 3] * wv;
            }
        }
        const float* rr = &tile[(y + 3) * 62 + x0 + 3];
        us4 o;
        o[0] = f2bf(a0 + cb + rr[0]);
        o[1] = f2bf(a1 + cb + rr[1]);
        o[2] = f2bf(a2 + cb + rr[2]);
        o[3] = f2bf(a3 + cb + rr[3]);
        *(us4*)(xpe + (size_t)bc * NN + y * NW + x0) = o;
    }
}

// ---------------- ALL weight -> B-fragment conversions in one launch ----------------
__global__ void wcvt_all_kernel(const float* __restrict__ Wf1, const float* __restrict__ Wv,
                                const float* __restrict__ Wf2, unsigned short* __restrict__ wf1,
                                unsigned short* __restrict__ wfpmq,
                                unsigned short* __restrict__ wfq,
                                unsigned short* __restrict__ wf2) {
    int z = blockIdx.z, nt = blockIdx.x, kc = blockIdx.y;
    const float* W;
    unsigned short* Bf;
    int ldw, rowoff, KC, NT;
    bool diff = false;
    if (z == 0) { W = Wf1; Bf = wf1; ldw = NC; rowoff = 0; KC = 6; NT = 3; }
    else if (z == 1) { W = Wv; Bf = wfpmq; ldw = NCOUT; rowoff = 0; KC = 6; NT = 6; diff = true; }
    else if (z == 2) { W = Wv; Bf = wfq; ldw = NCOUT; rowoff = NC; KC = 6; NT = 6; }
    else { W = Wf2; Bf = wf2; ldw = NC; rowoff = 0; KC = 12; NT = 3; }
    if (nt >= NT || kc >= KC) return;
    int tid = threadIdx.x;  // 256
    int c = tid >> 6, l = tid & 63;
    int n = l & 15, q = l >> 4;
    int col = nt * 64 + c * 16 + n;
    int krow = rowoff + kc * 32 + q * 8;
    unsigned short pack[8];
#pragma unroll
    for (int j = 0; j < 8; ++j) {
        float v = W[(size_t)(krow + j) * ldw + col];
        if (diff) v -= W[(size_t)(NC + krow + j) * ldw + col];
        pack[j] = f2bf(v);
    }
    *(us8*)(Bf + ((((size_t)nt * KC + kc) * 4 + c) * 64 + l) * 8) = *(const us8*)pack;
}

// ---------------- bf16 xpe [b][c][n] -> A-fragment for fc1 (pure repack) ----------------
__global__ __launch_bounds__(256) void tcvt_kernel(const unsigned short* __restrict__ xpe,
                                                   unsigned short* __restrict__ Af) {
    __shared__ unsigned short t[32][72];
    int b = blockIdx.z, kc = blockIdx.y, n0 = blockIdx.x * 64;
    int tid = threadIdx.x;
    int cl = tid >> 3, nl = (tid & 7) * 8;
    const unsigned short* src = xpe + ((size_t)b * NC + kc * 32 + cl) * NN + n0 + nl;
    *(us8*)&t[cl][nl] = *(const us8*)src;
    __syncthreads();
    int w = tid >> 6, l = tid & 63;
    int m = l & 15, q = l >> 4;
    int nloc = w * 16 + m;
    unsigned short pack[8];
#pragma unroll
    for (int j = 0; j < 8; ++j) pack[j] = t[q * 8 + j][nloc];
    int sg = blockIdx.x * 4 + w;
    *(us8*)(Af + (size_t)b * NN * NC + (((size_t)sg * 6 + kc) * 64 + l) * 8) =
        *(const us8*)pack;
}

// ---------------- LDS-free MFMA GEMM: fragment-streaming, fp32 out (+opt scatter/frag) ----------------
template <int KC>
__global__ __launch_bounds__(256) void gemm_mfma(const unsigned short* __restrict__ Af,
                                                 size_t aStride,
                                                 const unsigned short* __restrict__ Bf,
                                                 const float* __restrict__ bias,
                                                 float* __restrict__ C, size_t cStride,
                                                 int ldc, unsigned short* __restrict__ Cfrag,
                                                 const int* __restrict__ rowmap) {
    int b = blockIdx.z;
    int w = threadIdx.x >> 6, lane = threadIdx.x & 63;
    int sg = blockIdx.y * 4 + w;
    int n0 = blockIdx.x * 64;
    const unsigned short* Ap = Af + (size_t)b * aStride + ((size_t)sg * KC * 64 + lane) * 8;
    const unsigned short* Bp = Bf + ((size_t)blockIdx.x * KC * 256 + lane) * 8;
    f32x4 acc[4] = {};
#pragma unroll
    for (int kc = 0; kc < KC; ++kc) {
        s16x8 a = *(const s16x8*)(Ap + kc * 512);
#pragma unroll
        for (int c = 0; c < 4; ++c) {
            s16x8 bv = *(const s16x8*)(Bp + kc * 2048 + c * 512);
            acc[c] = __builtin_amdgcn_mfma_f32_16x16x32_bf16(a, bv, acc[c], 0, 0, 0);
        }
    }
    int col0 = lane & 15, rq = lane >> 4;
    float* Cb = C + (size_t)b * cStride;
    int kcd = ldc >> 5;
#pragma unroll
    for (int r = 0; r < 4; ++r) {
        int grow = sg * 16 + rq * 4 + r;
        int orow = rowmap ? rowmap[(size_t)b * NN + grow] : grow;
#pragma unroll
        for (int c = 0; c < 4; ++c) {
            int col = n0 + c * 16 + col0;
            float v = acc[c][r];
            if (bias) v += bias[col];
            Cb[(size_t)orow * ldc + col] = v;
            if (Cfrag) {
                int s2 = orow >> 4, m2 = orow & 15;
                int kc2 = col >> 5, q2 = (col >> 3) & 3, j2 = col & 7;
                Cfrag[(size_t)b * cStride +
                      (((size_t)s2 * kcd + kc2) * 64 + q2 * 16 + m2) * 8 + j2] = f2bf(v);
            }
        }
    }
}

// ---------------- merged P/Q GEMM: one A pass, two bf16 outputs ----------------
// PmQ = A @ (Wtop-Wbot) + bias (bf16); Qh = A @ Wbot (bf16). Row-major, sorted.
template <int KC>
__global__ __launch_bounds__(256) void gemm_mfma_pq(const unsigned short* __restrict__ Af,
                                                    size_t aStride,
                                                    const unsigned short* __restrict__ B1,
                                                    const unsigned short* __restrict__ B2,
                                                    const float* __restrict__ bias,
                                                    unsigned short* __restrict__ PmQ,
                                                    unsigned short* __restrict__ Qh,
                                                    size_t cStride, int ldc) {
    int b = blockIdx.z;
    int w = threadIdx.x >> 6, lane = threadIdx.x & 63;
    int sg = blockIdx.y * 4 + w;
    int n0 = blockIdx.x * 64;
    const unsigned short* Ap = Af + (size_t)b * aStride + ((size_t)sg * KC * 64 + lane) * 8;
    const unsigned short* Bp1 = B1 + ((size_t)blockIdx.x * KC * 256 + lane) * 8;
    const unsigned short* Bp2 = B2 + ((size_t)blockIdx.x * KC * 256 + lane) * 8;
    f32x4 acc1[4] = {};
    f32x4 acc2[4] = {};
#pragma unroll
    for (int kc = 0; kc < KC; ++kc) {
        s16x8 a = *(const s16x8*)(Ap + kc * 512);
#pragma unroll
        for (int c = 0; c < 4; ++c) {
            s16x8 b1 = *(const s16x8*)(Bp1 + kc * 2048 + c * 512);
            acc1[c] = __builtin_amdgcn_mfma_f32_16x16x32_bf16(a, b1, acc1[c], 0, 0, 0);
            s16x8 b2 = *(const s16x8*)(Bp2 + kc * 2048 + c * 512);
            acc2[c] = __builtin_amdgcn_mfma_f32_16x16x32_bf16(a, b2, acc2[c], 0, 0, 0);
        }
    }
    int col0 = lane & 15, rq = lane >> 4;
    unsigned short* Pb = PmQ + (size_t)b * cStride;
    unsigned short* Qb = Qh + (size_t)b * cStride;
#pragma unroll
    for (int r = 0; r < 4; ++r) {
        int grow = sg * 16 + rq * 4 + r;
#pragma unroll
        for (int c = 0; c < 4; ++c) {
            int col = n0 + c * 16 + col0;
            Pb[(size_t)grow * ldc + col] = f2bf(acc1[c][r] + bias[col]);
            Qb[(size_t)grow * ldc + col] = f2bf(acc2[c][r]);
        }
    }
}

// ---------------- fc2: bf16 out + bias + row scatter ----------------
template <int KC>
__global__ __launch_bounds__(256) void gemm_mfma_hb(const unsigned short* __restrict__ Af,
                                                    size_t aStride,
                                                    const unsigned short* __restrict__ Bf,
                                                    const float* __restrict__ bias,
                                                    unsigned short* __restrict__ C,
                                                    size_t cStride, int ldc,
                                                    const int* __restrict__ rowmap) {
    int b = blockIdx.z;
    int w = threadIdx.x >> 6, lane = threadIdx.x & 63;
    int sg = blockIdx.y * 4 + w;
    int n0 = blockIdx.x * 64;
    const unsigned short* Ap = Af + (size_t)b * aStride + ((size_t)sg * KC * 64 + lane) * 8;
    const unsigned short* Bp = Bf + ((size_t)blockIdx.x * KC * 256 + lane) * 8;
    f32x4 acc[4] = {};
#pragma unroll
    for (int kc = 0; kc < KC; ++kc) {
        s16x8 a = *(const s16x8*)(Ap + kc * 512);
#pragma unroll
        for (int c = 0; c < 4; ++c) {
            s16x8 bv = *(const s16x8*)(Bp + kc * 2048 + c * 512);
            acc[c] = __builtin_amdgcn_mfma_f32_16x16x32_bf16(a, bv, acc[c], 0, 0, 0);
        }
    }
    int col0 = lane & 15, rq = lane >> 4;
    unsigned short* Cb = C + (size_t)b * cStride;
#pragma unroll
    for (int r = 0; r < 4; ++r) {
        int grow = sg * 16 + rq * 4 + r;
        int orow = rowmap[(size_t)b * NN + grow];
#pragma unroll
        for (int c = 0; c < 4; ++c) {
            int col = n0 + c * 16 + col0;
            Cb[(size_t)orow * ldc + col] = f2bf(acc[c][r] + bias[col]);
        }
    }
}

// ---------------- xe = xs*rinv -> fp16 A-fragments; computes rinv + sqv in-kernel ----------------
__global__ __launch_bounds__(384) void xe_cvt_kernel(const float* __restrict__ xs,
                                                     const int* __restrict__ offk,
                                                     const int* __restrict__ cntk,
                                                     _Float16* __restrict__ xef,
                                                     float* __restrict__ sqv) {
    __shared__ float psum[16][25];
    __shared__ float rloc[16];
    int b = blockIdx.z, k = blockIdx.y, strip = blockIdx.x;
    int bk = b * NK + k;
    int base = offk[bk], L = cntk[bk];
    if (strip * 16 >= L) return;
    int kc = threadIdx.x >> 6, l = threadIdx.x & 63;
    int m = l & 15, q = l >> 4;
    int rl = strip * 16 + m;
    int row = base + (rl < L ? rl : L - 1);
    const float* src = xs + ((size_t)b * NN + row) * NC + kc * 32 + q * 8;
    float4 v0 = *(const float4*)src;
    float4 v1 = *(const float4*)(src + 4);
    float part = v0.x * v0.x + v0.y * v0.y + v0.z * v0.z + v0.w * v0.w + v1.x * v1.x +
                 v1.y * v1.y + v1.z * v1.z + v1.w * v1.w;
    psum[m][kc * 4 + q] = part;
    __syncthreads();
    if (threadIdx.x < 16) {
        float s = 0.0f;
#pragma unroll
        for (int i2 = 0; i2 < 24; ++i2) s += psum[threadIdx.x][i2];
        float nrm = fmaxf(sqrtf(s), 1e-12f);
        float ri = 1.0f / nrm;
        rloc[threadIdx.x] = ri;
        if (strip * 16 + (int)threadIdx.x < L)
            sqv[(size_t)b * NN + base + strip * 16 + threadIdx.x] = (s * ri) * ri;
    }
    __syncthreads();
    float rv = rloc[m];
    f16x8 pack;
    pack[0] = (_Float16)(v0.x * rv);
    pack[1] = (_Float16)(v0.y * rv);
    pack[2] = (_Float16)(v0.z * rv);
    pack[3] = (_Float16)(v0.w * rv);
    pack[4] = (_Float16)(v1.x * rv);
    pack[5] = (_Float16)(v1.y * rv);
    pack[6] = (_Float16)(v1.z * rv);
    pack[7] = (_Float16)(v1.w * rv);
    *(f16x8*)(xef + (size_t)bk * (20 * 6 * 512) + (((size_t)strip * 6 + kc) * 64 + l) * 8) =
        pack;
}

// ---------------- Gram -> d2 tiles via fp16 MFMA (stores only live rows/cols) ----------------
__global__ __launch_bounds__(256) void gram_kernel(const _Float16* __restrict__ xef,
                                                   const float* __restrict__ sqv,
                                                   const int* __restrict__ offk,
                                                   const int* __restrict__ cntk,
                                                   float* __restrict__ D) {
    int bk = blockIdx.z;
    int b = bk >> 4;
    int base = offk[bk], L = cntk[bk];
    int ti = blockIdx.x, tj = blockIdx.y;
    if (ti * 64 >= L || tj * 64 >= L) return;
    int w = threadIdx.x >> 6, lane = threadIdx.x & 63;
    const _Float16* Xf = xef + (size_t)bk * (20 * 6 * 512);
    const _Float16* Ap = Xf + (((size_t)(ti * 4 + w) * 6) * 64 + lane) * 8;
    f32x4 acc[4] = {};
#pragma unroll
    for (int kc = 0; kc < 6; ++kc) {
        f16x8 a = *(const f16x8*)(Ap + kc * 512);
#pragma unroll
        for (int js = 0; js < 4; ++js) {
            f16x8 bv = *(const f16x8*)(Xf + (((size_t)(tj * 4 + js) * 6 + kc) * 64 + lane) * 8);
            acc[js] = __builtin_amdgcn_mfma_f32_16x16x32_f16(a, bv, acc[js], 0, 0, 0);
        }
    }
    float* Dr = D + (size_t)bk * DSLOT;
    const float* Sb = sqv + (size_t)b * NN + base;
    int col0 = lane & 15, rq = lane >> 4;
#pragma unroll
    for (int r = 0; r < 4; ++r) {
        int i = ti * 64 + w * 16 + rq * 4 + r;
        if (i >= L) continue;
        float si = Sb[i];
#pragma unroll
        for (int js = 0; js < 4; ++js) {
            int j = tj * 64 + js * 16 + col0;
            if (j < L) Dr[(size_t)i * DSTRIDE + j] = si + Sb[j] - 2.0f * acc[js][r];
        }
    }
}

// ---------------- top-9 selection: one wave per row (sorted ids) ----------------
#define LEXLT(da, ca, db, cb) ((da) < (db) || ((da) == (db) && (ca) < (cb)))
__global__ __launch_bounds__(256) void select9_kernel(const float* __restrict__ D,
                                                      const int* __restrict__ lsv,
                                                      const int* __restrict__ offk,
                                                      const int* __restrict__ cntk,
                                                      int* __restrict__ nbr) {
    int b = blockIdx.y;
    int r = blockIdx.x * 4 + (threadIdx.x >> 6);
    int lane = threadIdx.x & 63;
    int k = lsv[(size_t)b * NN + r];
    int bk = b * NK + k;
    int base = offk[bk], L = cntk[bk];
    int Lc = L < LPMAX ? L : LPMAX;
    const float* Dr = D + (size_t)bk * DSLOT + (size_t)(r - base) * DSTRIDE;
    float d0, d1, d2, d3, d4;
    int c0, c1, c2, c3, c4;
    c0 = lane;
    c1 = lane + 64;
    c2 = lane + 128;
    c3 = lane + 192;
    c4 = lane + 256;
    d0 = c0 < Lc ? Dr[c0] : FLT_INF;
    d1 = c1 < Lc ? Dr[c1] : FLT_INF;
    d2 = c2 < Lc ? Dr[c2] : FLT_INF;
    d3 = c3 < Lc ? Dr[c3] : FLT_INF;
    d4 = c4 < Lc ? Dr[c4] : FLT_INF;
#define CS(da, ca, db, cb)                  \
    if (LEXLT(db, cb, da, ca)) {            \
        float t = da; da = db; db = t;      \
        int u = ca; ca = cb; cb = u;        \
    }
    CS(d0, c0, d1, c1) CS(d3, c3, d4, c4) CS(d2, c2, d4, c4) CS(d2, c2, d3, c3)
    CS(d1, c1, d4, c4) CS(d0, c0, d3, c3) CS(d0, c0, d2, c2) CS(d1, c1, d3, c3)
    CS(d1, c1, d2, c2)
#undef CS
    size_t row = (size_t)b * NN + r;
    for (int q = 0; q < KNB; ++q) {
        float bd = d0;
        int bc = c0;
#pragma unroll
        for (int m = 32; m; m >>= 1) {
            float od = __shfl_xor(bd, m, 64);
            int oc = __shfl_xor(bc, m, 64);
            if (LEXLT(od, oc, bd, bc)) {
                bd = od;
                bc = oc;
            }
        }
        if (lane == 0) nbr[row * KNB + q] = base + bc;
        if (d0 == bd && c0 == bc) {
            d0 = d1; c0 = c1;
            d1 = d2; c1 = c2;
            d2 = d3; c2 = c3;
            d3 = d4; c3 = c4;
            d4 = FLT_INF; c4 = 0x7fffffff;
        }
    }
}

// ---------------- centroids: 768 threads, 4 row-partitions x 192 channels ----------------
__global__ __launch_bounds__(768) void cen_kernel(const float* __restrict__ xs,
                                                  const int* __restrict__ offk,
                                                  const int* __restrict__ cntk,
                                                  float* __restrict__ cen) {
    __shared__ float part[4][NC];
    int bk = blockIdx.x;
    int b = bk >> 4;
    int base = offk[bk], L = cntk[bk];
    int w = threadIdx.x / NC;  // 0..3 row partition
    int c = threadIdx.x % NC;
    const float* Xb = xs + ((size_t)b * NN + base) * NC + c;
    float s = 0.0f;
    for (int r = w; r < L; r += 4) s += Xb[(size_t)r * NC];
    part[w][c] = s;
    __syncthreads();
    if (threadIdx.x < NC) {
        int cc = threadIdx.x;
        float tot = part[0][cc] + part[1][cc] + part[2][cc] + part[3][cc];
        cen[(size_t)bk * NC + cc] = tot / fmaxf((float)L, 1.0f);
    }
}

// ---------------- cluster P/Q (128 blocks) ----------------
__global__ __launch_bounds__(384) void pcqc_kernel(const float* __restrict__ cen,
                                                   const float* __restrict__ Wc,
                                                   const float* __restrict__ bc,
                                                   float* __restrict__ Pc,
                                                   float* __restrict__ Qc) {
    __shared__ float ce[NC];
    int bk = blockIdx.x;
    int o = threadIdx.x;  // 384
    if (o < NC) ce[o] = cen[(size_t)bk * NC + o];
    __syncthreads();
    float pc = bc[o], qc = 0.0f;
    for (int c = 0; c < NC; ++c) {
        pc += ce[c] * Wc[(size_t)c * NCOUT + o];
        qc += ce[c] * Wc[(size_t)(NC + c) * NCOUT + o];
    }
    Pc[(size_t)bk * NCOUT + o] = pc;
    Qc[(size_t)bk * NCOUT + o] = qc;
}

// ---------------- cluster message max (valley trick, 128 blocks) ----------------
__global__ __launch_bounds__(384) void hcmax_kernel(const float* __restrict__ Pc,
                                                    const float* __restrict__ Qc,
                                                    float* __restrict__ hc) {
    int b = blockIdx.x >> 4, i = blockIdx.x & 15;
    int o = threadIdx.x;
    float pi = Pc[((size_t)b * NK + i) * NCOUT + o];
    float qi = Qc[((size_t)b * NK + i) * NCOUT + o];
    float pmq = pi - qi;
    float qmn = FLT_INF, qmx = -FLT_INF;
    for (int j = 0; j < NK; ++j) {
        float v = Qc[((size_t)b * NK + j) * NCOUT + o];
        qmn = fminf(qmn, v);
        qmx = fmaxf(qmx, v);
    }
    hc[((size_t)b * NK + i) * NCOUT + o] =
        fmaxf(gelu_t(pmq + qmn), gelu_t(pmq + qmx));
}

// ---------------- node max + cluster term -> hn bf16 A-fragments (sorted order) ----------------
__global__ __launch_bounds__(256) void hv_kernel(const unsigned short* __restrict__ PmQ,
                                                 const unsigned short* __restrict__ Qh,
                                                 const int* __restrict__ nbr,
                                                 const int* __restrict__ lsv,
                                                 const float* __restrict__ hc,
                                                 unsigned short* __restrict__ hnf) {
    __shared__ float hnv[4][NCOUT];
    int b = blockIdx.y;
    int w = threadIdx.x >> 6, lane = threadIdx.x & 63;
    int i = blockIdx.x * 4 + w;
    size_t row = (size_t)b * NN + i;
    const unsigned short* Pr = PmQ + row * NCOUT;
    int lab = lsv[row];
    const float* hcr = hc + ((size_t)b * NK + lab) * NCOUT;
    int jn[KNB];
#pragma unroll
    for (int q = 0; q < KNB; ++q) jn[q] = nbr[row * KNB + q];
    const unsigned short* Qbb = Qh + (size_t)b * NN * NCOUT;
#pragma unroll
    for (int u = 0; u < 6; ++u) {
        int o = lane + 64 * u;
        float pmq = bf2f(Pr[o]);
        float q0 = bf2f(Qbb[(size_t)jn[0] * NCOUT + o]);
        float qmn = q0, qmx = q0;
#pragma unroll
        for (int q = 1; q < KNB; ++q) {
            float v = bf2f(Qbb[(size_t)jn[q] * NCOUT + o]);
            qmn = fminf(qmn, v);
            qmx = fmaxf(qmx, v);
        }
        float m = fmaxf(gelu_t(pmq + qmn), gelu_t(pmq + qmx));
        hnv[w][o] = m + hcr[o];
    }
    __syncthreads();
    if (threadIdx.x < 192) {  // 4 rows x 48 chunks of 8 -> us8 stores
        int rsub = threadIdx.x / 48, c = threadIdx.x % 48;
        int i2 = blockIdx.x * 4 + rsub;
        int s = i2 >> 4, mm = i2 & 15;
        unsigned short pack[8];
#pragma unroll
        for (int e = 0; e < 8; ++e) pack[e] = f2bf(hnv[rsub][c * 8 + e]);
        *(us8*)(hnf + (size_t)b * NN * NCOUT +
                (((size_t)s * 12 + (c >> 2)) * 64 + (c & 3) * 16 + mm) * 8) =
            *(const us8*)pack;
    }
}

// ---------------- transpose (b,n,c)->(b,c,n) + residual (bf16 in, fp32 out) ----------------
__global__ void out_kernel(const unsigned short* __restrict__ T, const float* __restrict__ X,
                           float* __restrict__ Y) {
    __shared__ float t[32][33];
    int b = blockIdx.z;
    int n0 = blockIdx.y * 32, c0 = blockIdx.x * 32;
    int tx = threadIdx.x, ty = threadIdx.y;  // 32 x 8
#pragma unroll
    for (int q = 0; q < 4; ++q) {
        int n = n0 + ty + q * 8;
        t[ty + q * 8][tx] = bf2f(T[((size_t)b * NN + n) * NC + c0 + tx]);
    }
    __syncthreads();
#pragma unroll
    for (int q = 0; q < 4; ++q) {
        int c = c0 + ty + q * 8;
        size_t idx = ((size_t)b * NC + c) * NN + n0 + tx;
        Y[idx] = t[tx][ty + q * 8] + X[idx];
    }
}

extern "C" void kernel_launch(void* const* d_in, const int* in_sizes, int n_in, void* d_out,
                              int out_size, void* d_ws, size_t ws_size, hipStream_t stream) {
    const float* x = (const float*)d_in[0];
    const int* labels = (const int*)d_in[1];
    const float* cpe_w = (const float*)d_in[2];
    const float* cpe_b = (const float*)d_in[3];
    const float* fc1_w = (const float*)d_in[4];
    const float* fc1_b = (const float*)d_in[5];
    const float* nn_v_w = (const float*)d_in[6];
    const float* nn_v_b = (const float*)d_in[7];
    const float* nn_c_w = (const float*)d_in[8];
    const float* nn_c_b = (const float*)d_in[9];
    const float* fc2_w = (const float*)d_in[10];
    const float* fc2_b = (const float*)d_in[11];
    float* out = (float*)d_out;

    const size_t SZ_XS = (size_t)NB * NN * NC;
    const size_t SZ_P = (size_t)NB * NN * NCOUT;
    const size_t BN = (size_t)NB * NN;
    const size_t SZ_CEN = (size_t)NB * NK * NC;
    const size_t SZ_PC = (size_t)NB * NK * NCOUT;

    float* base = (float*)d_ws;
    float* xs = base;                 // sorted fc1 out (fp32); reused as bf16 out_t later
    float* xpeRegion = xs + SZ_XS;    // bf16 conv out (ushort)
    float* Pb = xpeRegion + SZ_XS;    // bf16 PmQ (sorted); Dbuf during knn
    float* Qb = Pb + SZ_P;            // bf16 Qh (sorted)
    float* rinv = Qb + SZ_P;          // unused slot (kept for layout stability)
    float* sqv = rinv + BN;
    float* cen = sqv + BN;
    float* Pc = cen + SZ_CEN;
    float* Qc = Pc + SZ_PC;
    float* hcv = Qc + SZ_PC;
    int* order = (int*)(hcv + SZ_PC);
    int* mapping = order + BN;
    int* lsv = mapping + BN;
    int* nbrv = lsv + BN;
    int* cntk = nbrv + BN * KNB;
    int* offk = cntk + NB * NK;
    unsigned short* xpe = (unsigned short*)xpeRegion;
    float* Dbuf = Pb;  // spans Pb..Qb, dead before the P/Q gemm
    unsigned short* PmQh = (unsigned short*)Pb;
    unsigned short* Qh = (unsigned short*)Qb;
    unsigned short* out_t = (unsigned short*)xs;  // xs fp32 dead after cen
    unsigned short* frag = (unsigned short*)(offk + NB * NK);
    unsigned short* xpeT_frag = frag;
    unsigned short* xs_frag = frag + SZ_XS;
    unsigned short* hn_frag = frag;  // alias, xpeT dead by hv time
    unsigned short* wf1 = frag + 2 * SZ_XS;
    unsigned short* wfpmq = wf1 + (size_t)NC * NC;    // (Wtop-Wbot) 192x384
    unsigned short* wfq = wfpmq + (size_t)NC * NCOUT; // Wbot 192x384
    unsigned short* wf2 = wfq + (size_t)NC * NCOUT;
    _Float16* xef = (_Float16*)(wf2 + (size_t)NCOUT * NC);

    order_kernel<<<NB * NK, 64, 0, stream>>>(labels, order, mapping, lsv, cntk, offk);
    wcvt_all_kernel<<<dim3(6, 12, 4), 256, 0, stream>>>(fc1_w, nn_v_w, fc2_w, wf1, wfpmq,
                                                        wfq, wf2);
    conv_kernel<<<NB * NC, 256, 0, stream>>>(x, cpe_w, cpe_b, xpe);
    tcvt_kernel<<<dim3(NN / 64, NC / 32, NB), 256, 0, stream>>>(xpe, xpeT_frag);
    // fc1: rows scattered to sorted order; xs fp32 + xs_frag bf16 (sorted)
    gemm_mfma<6><<<dim3(NC / 64, NN / 64, NB), 256, 0, stream>>>(
        xpeT_frag, SZ_XS / NB, wf1, fc1_b, xs, (size_t)NN * NC, NC, xs_frag, mapping);
    // xe fragments + rinv/sqv fused
    xe_cvt_kernel<<<dim3(LPMAX / 16, NK, NB), 384, 0, stream>>>(xs, offk, cntk, xef, sqv);
    gram_kernel<<<dim3(LPMAX / 64, LPMAX / 64, NB * NK), 256, 0, stream>>>(xef, sqv, offk,
                                                                           cntk, Dbuf);
    select9_kernel<<<dim3(NN / 4, NB), 256, 0, stream>>>(Dbuf, lsv, offk, cntk, nbrv);
    // merged: PmQ = xs@(Wtop-Wbot)+bias (bf16), Qh = xs@Wbot (bf16) — one A pass
    gemm_mfma_pq<6><<<dim3(NCOUT / 64, NN / 64, NB), 256, 0, stream>>>(
        xs_frag, SZ_XS / NB, wfpmq, wfq, nn_v_b, PmQh, Qh, (size_t)NN * NCOUT, NCOUT);
    cen_kernel<<<NB * NK, 768, 0, stream>>>(xs, offk, cntk, cen);
    pcqc_kernel<<<NB * NK, NCOUT, 0, stream>>>(cen, nn_c_w, nn_c_b, Pc, Qc);
    hcmax_kernel<<<NB * NK, NCOUT, 0, stream>>>(Pc, Qc, hcv);
    hv_kernel<<<dim3(NN / 4, NB), 256, 0, stream>>>(PmQh, Qh, nbrv, lsv, hcv, hn_frag);
    // fc2: sorted rows -> bf16 out_t scattered to spatial order (xs region, fp32 xs dead)
    gemm_mfma_hb<12><<<dim3(NC / 64, NN / 64, NB), 256, 0, stream>>>(
        hn_frag, SZ_P / NB, wf2, fc2_b, out_t, (size_t)NN * NC, NC, order);
    out_kernel<<<dim3(NC / 32, NN / 32, NB), dim3(32, 8), 0, stream>>>(out_t, x, out);
}